// Round 7
// baseline (132.651 us; speedup 1.0000x reference)
//
#include <hip/hip_runtime.h>

#define EMB 64
#define HEADS 8
#define SEQ 2048
#define LSF 68

typedef short short8 __attribute__((ext_vector_type(8)));
typedef float f32x4 __attribute__((ext_vector_type(4)));
typedef unsigned int u32;
typedef unsigned long long u64;

__device__ __forceinline__ float4 ld4(const float* p) { return *(const float4*)p; }
__device__ __forceinline__ float4 fmad4(float4 a, float s, float4 c) {
  c.x += a.x*s; c.y += a.y*s; c.z += a.z*s; c.w += a.w*s; return c;
}
__device__ __forceinline__ unsigned short f2bf(float f) {
  union { float f; unsigned u; } x; x.f = f;
  return (unsigned short)((x.u + 0x7fffu + ((x.u >> 16) & 1u)) >> 16);
}
__device__ __forceinline__ float bf2f(unsigned short s) {
  union { unsigned u; float f; } x; x.u = ((unsigned)s) << 16;
  return x.f;
}
__device__ __forceinline__ float bits2f(u32 u) {
  union { u32 u; float f; } x; x.u = u;
  return x.f;
}
__device__ __forceinline__ u32 cvtpk(float lo, float hi) {
  u32 r;
  asm("v_cvt_pk_bf16_f32 %0, %1, %2" : "=v"(r) : "v"(lo), "v"(hi));
  return r;
}
// 2 lsbs of b -> bf16 AND-mask word: bit0 -> lo16, bit1 -> hi16
__device__ __forceinline__ u32 expand2(u32 b) {
  return ((b & 1u) ? 0xFFFFu : 0u) | ((b & 2u) ? 0xFFFF0000u : 0u);
}
__device__ __forceinline__ void gload16(const void* g, void* l) {
  __builtin_amdgcn_global_load_lds((const __attribute__((address_space(1))) unsigned int*)g,
                                   (__attribute__((address_space(3))) unsigned int*)l, 16, 0, 0);
}

// ---- mask -> bits, TRANSPOSED layout: bits[kt*2048 + qrow], bit j = mask[qrow][kt*64+j] ----
__global__ __launch_bounds__(256) void maskbits_kernel(const int* __restrict__ mask,
                                                       u64* __restrict__ bits) {
  const int gid = blockIdx.x * 256 + threadIdx.x;   // 4M threads
  const int w_ = gid >> 6, lane = gid & 63;
  const int kt = w_ >> 11, row = w_ & 2047;
  const u64 b = __ballot(mask[(size_t)row * SEQ + kt * 64 + lane] != 0);
  if (lane == 0) bits[w_] = b;
}

// ---- projections -> bf16: z=0 K [bh][t][64], z=1 V^T [bh][64][t], z=2 Q*0.125 ----
__global__ __launch_bounds__(256) void proj_kernel(
    const float* __restrict__ x, const float* __restrict__ y,
    const float* __restrict__ Wk, const float* __restrict__ Wq, const float* __restrict__ Wv,
    unsigned short* __restrict__ Kbuf, unsigned short* __restrict__ Qbuf,
    unsigned short* __restrict__ VbufT)
{
  __shared__ float As[64][LSF];
  __shared__ float Bs[64][LSF];
  const int t = threadIdx.x;
  const int rowblk = blockIdx.x;   // 0..127 over B*T/64
  const int h = blockIdx.y;        // 0..7
  const int z = blockIdx.z;        // 0:K 1:V^T 2:Q
  const float* __restrict__ in = (z == 2) ? y : x;
  const float* __restrict__ W = (z == 0) ? Wk : (z == 1) ? Wv : Wq;

  for (int i = t; i < 1024; i += 256) {
    const int r = i >> 4, c4 = (i & 15) << 2;
    *(float4*)&As[r][c4] = ld4(&in[(size_t)(rowblk*64 + r)*EMB + c4]);
    *(float4*)&Bs[r][c4] = ld4(&W[(size_t)r*(EMB*HEADS) + h*EMB + c4]);
  }
  __syncthreads();

  const int tr = (t >> 4) << 2;
  const int tc = (t & 15) << 2;
  float4 acc[4];
  #pragma unroll
  for (int i = 0; i < 4; ++i) acc[i] = (float4){0,0,0,0};
  #pragma unroll 8
  for (int k = 0; k < 64; ++k) {
    const float4 w = *(const float4*)&Bs[k][tc];
    #pragma unroll
    for (int i = 0; i < 4; ++i) acc[i] = fmad4(w, As[tr+i][k], acc[i]);
  }

  const int b = rowblk >> 5;
  const int tbase = (rowblk & 31) * 64;
  const int bh = b * HEADS + h;
  const float scale = (z == 2) ? 0.125f : 1.0f;

  if (z != 1) {
    unsigned short* __restrict__ dst = (z == 0) ? Kbuf : Qbuf;
    #pragma unroll
    for (int i = 0; i < 4; ++i) {
      ushort4 o;
      o.x = f2bf(acc[i].x * scale); o.y = f2bf(acc[i].y * scale);
      o.z = f2bf(acc[i].z * scale); o.w = f2bf(acc[i].w * scale);
      *(ushort4*)&dst[((size_t)bh*SEQ + tbase + tr + i)*EMB + tc] = o;
    }
  } else {
    __syncthreads();
    #pragma unroll
    for (int i = 0; i < 4; ++i) {
      As[tc+0][tr+i] = acc[i].x; As[tc+1][tr+i] = acc[i].y;
      As[tc+2][tr+i] = acc[i].z; As[tc+3][tr+i] = acc[i].w;
    }
    __syncthreads();
    #pragma unroll
    for (int i = 0; i < 4; ++i) {   // row tr+i = feature
      ushort4 o;
      o.x = f2bf(As[tr+i][tc+0]); o.y = f2bf(As[tr+i][tc+1]);
      o.z = f2bf(As[tr+i][tc+2]); o.w = f2bf(As[tr+i][tc+3]);
      *(ushort4*)&VbufT[((size_t)bh*EMB + tr + i)*SEQ + tbase + tc] = o;
    }
  }
}

// ---- flash: R4-proven structure; ONLY change = bit-mask (transposed) replacing Pmask ----
__global__ __launch_bounds__(256, 4) void flash_kernel(
    const unsigned short* __restrict__ Qbuf, const unsigned short* __restrict__ Kbuf,
    const unsigned short* __restrict__ VbufT, const u64* __restrict__ mbits,
    unsigned short* __restrict__ Oint)
{
  __shared__ alignas(16) char smem[40960];
  char* const K0 = smem;
  char* const K1 = smem + 8192;
  char* const V0 = smem + 16384;
  char* const V1 = smem + 24576;

  const int t = threadIdx.x;
  const int w = t >> 6, l = t & 63, g = l >> 4, q = l & 15;
  const int id = blockIdx.x;
  const int k_ = id >> 3;
  const int bh = (id & 7) * 4 + (k_ >> 5);   // XCD-aware: per-XCD K/V L2-resident
  const int qblk = k_ & 31;
  const int b = bh >> 3, h = bh & 7;

  // Q fragment (B-operand): lane holds Q[qrow=qblk*64+w*16+q][feat = 32kk+8g+j]
  short8 qf[2];
  {
    const unsigned short* qp = Qbuf + ((size_t)bh*SEQ + qblk*64 + w*16 + q)*EMB + g*8;
    qf[0] = *(const short8*)qp;
    qf[1] = *(const short8*)(qp + 32);
  }

  f32x4 oacc[4];
  #pragma unroll
  for (int c = 0; c < 4; ++c) oacc[c] = (f32x4){0.f,0.f,0.f,0.f};
  float lsum = 0.f;                          // row-sum for qrow = w*16 + q (replicated over g)

  char* const Pw = smem + 32768 + w*2048;    // wave-private P: 16 rows x 128B
  const int sw = (q & 7) << 4;

  const u64* __restrict__ mbase = mbits + qblk*64 + w*16 + q;   // + kt*2048

  #define STAGE(KT, KDST, VDST) do {                                                  \
    _Pragma("unroll")                                                                 \
    for (int p = 0; p < 2; ++p) {                                                     \
      const int unit = p*256 + w*64 + l;                                              \
      const int row_ = unit >> 3;                                                     \
      const int gsrc = (unit & 7) ^ (row_ & 7);                                       \
      gload16(Kbuf + ((size_t)bh*SEQ + (KT)*64 + row_)*EMB + gsrc*8,                  \
              (KDST) + (p*256 + w*64)*16);                                            \
      gload16(VbufT + ((size_t)bh*EMB + row_)*SEQ + (KT)*64 + gsrc*8,                 \
              (VDST) + (p*256 + w*64)*16);                                            \
    }                                                                                 \
  } while (0)

  STAGE(0, K0, V0);
  __syncthreads();

  // lane's S entries: sacc[c][r] = S[key = kt*64 + 16c + 4g + r][qrow = w*16 + q]
  #define TILE(KT, kbase, vbase, DOSTAGE, nkbase, nvbase) do {                         \
    const u64 mw = mbase[(size_t)(KT)*2048];                                           \
    const u64 sh = mw >> (4*g);                                                        \
    const u32 blo = (u32)sh, bhi2 = (u32)(sh >> 32);                                   \
    f32x4 sacc[4];                                                                     \
    _Pragma("unroll") for (int c = 0; c < 4; ++c) {                                    \
      sacc[c] = (f32x4){0.f,0.f,0.f,0.f};                                              \
      _Pragma("unroll") for (int kk = 0; kk < 2; ++kk) {                               \
        const short8 kf = *(const short8*)((kbase) + (16*c + q)*128 + (((kk*4+g)<<4) ^ sw)); \
        sacc[c] = __builtin_amdgcn_mfma_f32_16x16x32_bf16(kf, qf[kk], sacc[c], 0,0,0); \
      }                                                                                \
    }                                                                                  \
    u32 pw[8];                                                                         \
    _Pragma("unroll") for (int c = 0; c < 4; ++c) {                                    \
      const u32 bb = (c < 2) ? (blo >> (16*c)) : (bhi2 >> (16*(c-2)));                 \
      const float p0 = __expf(sacc[c][0] - 4.f);                                       \
      const float p1 = __expf(sacc[c][1] - 4.f);                                       \
      const float p2 = __expf(sacc[c][2] - 4.f);                                       \
      const float p3 = __expf(sacc[c][3] - 4.f);                                       \
      pw[2*c]   = cvtpk(p0, p1) & expand2(bb);                                         \
      pw[2*c+1] = cvtpk(p2, p3) & expand2(bb >> 2);                                    \
    }                                                                                  \
    _Pragma("unroll") for (int c = 0; c < 4; ++c)                                      \
      *(uint2*)(Pw + ((q*128 + 32*c + 8*g) ^ sw)) = make_uint2(pw[2*c], pw[2*c+1]);    \
    /* register l-sum from the exact masked bf16 bits PV will consume */               \
    float ts = 0.f;                                                                    \
    _Pragma("unroll") for (int i = 0; i < 8; ++i)                                      \
      ts += bits2f(pw[i] << 16) + bits2f(pw[i] & 0xFFFF0000u);                         \
    ts += __shfl_xor(ts, 16);                                                          \
    ts += __shfl_xor(ts, 32);                                                          \
    lsum += ts;                                                                        \
    __syncthreads();  /* P visible; prev K/V reads done */                             \
    if (DOSTAGE) STAGE((KT)+1, nkbase, nvbase);                                        \
    short8 pf[2];                                                                      \
    pf[0] = *(const short8*)(Pw + ((q*128 + 16*g) ^ sw));                              \
    pf[1] = *(const short8*)(Pw + ((q*128 + 64 + 16*g) ^ sw));                         \
    _Pragma("unroll") for (int c = 0; c < 4; ++c) {                                    \
      _Pragma("unroll") for (int kk = 0; kk < 2; ++kk) {                               \
        const short8 vf = *(const short8*)((vbase) + (16*c + q)*128 + (((kk*4+g)<<4) ^ sw)); \
        oacc[c] = __builtin_amdgcn_mfma_f32_16x16x32_bf16(pf[kk], vf, oacc[c], 0,0,0); \
      }                                                                                \
    }                                                                                  \
    __syncthreads();                                                                   \
  } while (0)

  #pragma unroll 1
  for (int kt2 = 0; kt2 < 16; ++kt2) {
    TILE(2*kt2,   K0, V0, true,       K1, V1);
    TILE(2*kt2+1, K1, V1, (kt2 < 15), K0, V0);
  }
  #undef TILE
  #undef STAGE

  // epilogue: oacc[c][r] = O[qrow = w*16 + 4g + r][feat = q + 16c]; lsum at lane (g, qrow&15)
  #pragma unroll
  for (int r = 0; r < 4; ++r) {
    const float lr = __shfl(lsum, (l & 48) | (4*g + r));
    const float inv = (lr > 1e-30f) ? 1.f / lr : 0.f;
    #pragma unroll
    for (int c = 0; c < 4; ++c) {
      Oint[((size_t)b*SEQ + qblk*64 + w*16 + 4*g + r)*(EMB*HEADS) + h*EMB + q + 16*c] =
          f2bf(oacc[c][r] * inv);
    }
  }
}

// ---- output projection: bf16 [8192,512] @ fp32 [512,64] + bu (round-4 proven version) ----
__global__ __launch_bounds__(256) void outproj_kernel(
    const unsigned short* __restrict__ Oint, const float* __restrict__ Wu,
    const float* __restrict__ bu, float* __restrict__ out)
{
  __shared__ float As[64][LSF];
  __shared__ float Ws[64][LSF];
  const int t = threadIdx.x;
  const int rowblk = blockIdx.x;   // 0..127
  const int tr = (t >> 4) << 2;
  const int tc = (t & 15) << 2;
  float4 acc[4];
  #pragma unroll
  for (int i = 0; i < 4; ++i) acc[i] = (float4){0,0,0,0};

  for (int kt = 0; kt < 8; ++kt) {
    for (int i = t; i < 512; i += 256) {
      const int r = i >> 3, c8 = (i & 7) << 3;
      const short8 v = *(const short8*)&Oint[(size_t)(rowblk*64 + r)*(EMB*HEADS) + kt*64 + c8];
      #pragma unroll
      for (int j = 0; j < 8; ++j) As[r][c8 + j] = bf2f((unsigned short)v[j]);
    }
    for (int i = t; i < 1024; i += 256) {
      const int r = i >> 4, c4 = (i & 15) << 2;
      *(float4*)&Ws[r][c4] = ld4(&Wu[(size_t)(kt*64 + r)*EMB + c4]);
    }
    __syncthreads();
    #pragma unroll 8
    for (int k = 0; k < 64; ++k) {
      const float4 w = *(const float4*)&Ws[k][tc];
      #pragma unroll
      for (int i = 0; i < 4; ++i) acc[i] = fmad4(w, As[tr+i][k], acc[i]);
    }
    __syncthreads();
  }
  const float4 bv = ld4(&bu[tc]);
  #pragma unroll
  for (int i = 0; i < 4; ++i) {
    float4 r = acc[i];
    r.x += bv.x; r.y += bv.y; r.z += bv.z; r.w += bv.w;
    *(float4*)&out[(size_t)(rowblk*64 + tr + i)*EMB + tc] = r;
  }
}

extern "C" void kernel_launch(void* const* d_in, const int* in_sizes, int n_in,
                              void* d_out, int out_size, void* d_ws, size_t ws_size,
                              hipStream_t stream) {
  const float* x   = (const float*)d_in[0];
  const float* y   = (const float*)d_in[1];
  const int*   mask= (const int*)d_in[2];
  const float* Wk  = (const float*)d_in[3];
  const float* Wq  = (const float*)d_in[4];
  const float* Wv  = (const float*)d_in[5];
  const float* Wu  = (const float*)d_in[6];
  const float* bu  = (const float*)d_in[7];
  float* out = (float*)d_out;

  // ws: Qbuf(8M) | Kbuf(8M) | VbufT(8M) | mbits(512K) | Oint bf16(8M) = 33 MiB
  unsigned short* Qbuf  = (unsigned short*)d_ws;
  unsigned short* Kbuf  = Qbuf + (size_t)32*SEQ*EMB;
  unsigned short* VbufT = Kbuf + (size_t)32*SEQ*EMB;
  u64* mbits = (u64*)((char*)d_ws + (size_t)24*1024*1024);
  unsigned short* Oint = (unsigned short*)((char*)d_ws + (size_t)25*1024*1024);

  maskbits_kernel<<<16384, 256, 0, stream>>>(mask, mbits);
  proj_kernel<<<dim3(128, 8, 3), 256, 0, stream>>>(x, y, Wk, Wq, Wv, Kbuf, Qbuf, VbufT);
  flash_kernel<<<1024, 256, 0, stream>>>(Qbuf, Kbuf, VbufT, mbits, Oint);
  outproj_kernel<<<128, 256, 0, stream>>>(Oint, Wu, bu, out);
}

// Round 8
// 125.429 us; speedup vs baseline: 1.0576x; 1.0576x over previous
//
#include <hip/hip_runtime.h>

#define EMB 64
#define HEADS 8
#define SEQ 2048
#define LSF 68

typedef short short8 __attribute__((ext_vector_type(8)));
typedef float f32x4 __attribute__((ext_vector_type(4)));
typedef unsigned int u32;
typedef unsigned long long u64;

__device__ __forceinline__ float4 ld4(const float* p) { return *(const float4*)p; }
__device__ __forceinline__ float4 fmad4(float4 a, float s, float4 c) {
  c.x += a.x*s; c.y += a.y*s; c.z += a.z*s; c.w += a.w*s; return c;
}
__device__ __forceinline__ unsigned short f2bf(float f) {
  union { float f; unsigned u; } x; x.f = f;
  return (unsigned short)((x.u + 0x7fffu + ((x.u >> 16) & 1u)) >> 16);
}
__device__ __forceinline__ float bf2f(unsigned short s) {
  union { unsigned u; float f; } x; x.u = ((unsigned)s) << 16;
  return x.f;
}
__device__ __forceinline__ float bits2f(u32 u) {
  union { u32 u; float f; } x; x.u = u;
  return x.f;
}
__device__ __forceinline__ u32 cvtpk(float lo, float hi) {
  u32 r;
  asm("v_cvt_pk_bf16_f32 %0, %1, %2" : "=v"(r) : "v"(lo), "v"(hi));
  return r;
}
__device__ __forceinline__ float vexp2(float x) {
  float r;
  asm("v_exp_f32 %0, %1" : "=v"(r) : "v"(x));
  return r;
}
__device__ __forceinline__ void gload16(const void* g, void* l) {
  __builtin_amdgcn_global_load_lds((const __attribute__((address_space(1))) unsigned int*)g,
                                   (__attribute__((address_space(3))) unsigned int*)l, 16, 0, 0);
}

#define LOG2E 1.4426950408889634f
#define NC0  (-5.770780163555854f)   /* -4 * log2(e) */

// ---- mask -> packed bf16 AND-words in flash's exact per-lane order (R4-proven) ----
// word gid = qblk*65536 + kt*2048 + w*512 + l*8 + i ; covers keys (k,k+1) for
// q = qblk*64 + w*16 + (l&15), g = l>>4, c = i>>1, rr = i&1, k = kt*64 + 16c + 4g + 2rr
__global__ __launch_bounds__(256) void packmask_kernel(const int* __restrict__ mask,
                                                       u32* __restrict__ pmask) {
  const int gid = blockIdx.x * 256 + threadIdx.x;       // 2M words
  const int i = gid & 7, l = (gid >> 3) & 63, w = (gid >> 9) & 3;
  const int kt = (gid >> 11) & 31, qblk = gid >> 16;
  const int q = qblk*64 + w*16 + (l & 15);
  const int g = l >> 4, c = i >> 1, rr = i & 1;
  const int k = kt*64 + 16*c + 4*g + 2*rr;
  const int2 mm = *(const int2*)&mask[(size_t)q * SEQ + k];
  pmask[gid] = (mm.x ? 0xFFFFu : 0u) | (mm.y ? 0xFFFF0000u : 0u);
}

// ---- projections -> bf16: z=0 K [bh][t][64], z=1 V^T [bh][64][t], z=2 Q*0.125 ----
__global__ __launch_bounds__(256) void proj_kernel(
    const float* __restrict__ x, const float* __restrict__ y,
    const float* __restrict__ Wk, const float* __restrict__ Wq, const float* __restrict__ Wv,
    unsigned short* __restrict__ Kbuf, unsigned short* __restrict__ Qbuf,
    unsigned short* __restrict__ VbufT)
{
  __shared__ float As[64][LSF];
  __shared__ float Bs[64][LSF];
  const int t = threadIdx.x;
  const int rowblk = blockIdx.x;   // 0..127 over B*T/64
  const int h = blockIdx.y;        // 0..7
  const int z = blockIdx.z;        // 0:K 1:V^T 2:Q
  const float* __restrict__ in = (z == 2) ? y : x;
  const float* __restrict__ W = (z == 0) ? Wk : (z == 1) ? Wv : Wq;

  for (int i = t; i < 1024; i += 256) {
    const int r = i >> 4, c4 = (i & 15) << 2;
    *(float4*)&As[r][c4] = ld4(&in[(size_t)(rowblk*64 + r)*EMB + c4]);
    *(float4*)&Bs[r][c4] = ld4(&W[(size_t)r*(EMB*HEADS) + h*EMB + c4]);
  }
  __syncthreads();

  const int tr = (t >> 4) << 2;
  const int tc = (t & 15) << 2;
  float4 acc[4];
  #pragma unroll
  for (int i = 0; i < 4; ++i) acc[i] = (float4){0,0,0,0};
  #pragma unroll 8
  for (int k = 0; k < 64; ++k) {
    const float4 w = *(const float4*)&Bs[k][tc];
    #pragma unroll
    for (int i = 0; i < 4; ++i) acc[i] = fmad4(w, As[tr+i][k], acc[i]);
  }

  const int b = rowblk >> 5;
  const int tbase = (rowblk & 31) * 64;
  const int bh = b * HEADS + h;
  const float scale = (z == 2) ? 0.125f : 1.0f;

  if (z != 1) {
    unsigned short* __restrict__ dst = (z == 0) ? Kbuf : Qbuf;
    #pragma unroll
    for (int i = 0; i < 4; ++i) {
      ushort4 o;
      o.x = f2bf(acc[i].x * scale); o.y = f2bf(acc[i].y * scale);
      o.z = f2bf(acc[i].z * scale); o.w = f2bf(acc[i].w * scale);
      *(ushort4*)&dst[((size_t)bh*SEQ + tbase + tr + i)*EMB + tc] = o;
    }
  } else {
    __syncthreads();
    #pragma unroll
    for (int i = 0; i < 4; ++i) {
      As[tc+0][tr+i] = acc[i].x; As[tc+1][tr+i] = acc[i].y;
      As[tc+2][tr+i] = acc[i].z; As[tc+3][tr+i] = acc[i].w;
    }
    __syncthreads();
    #pragma unroll
    for (int i = 0; i < 4; ++i) {   // row tr+i = feature
      ushort4 o;
      o.x = f2bf(As[tr+i][tc+0]); o.y = f2bf(As[tr+i][tc+1]);
      o.z = f2bf(As[tr+i][tc+2]); o.w = f2bf(As[tr+i][tc+3]);
      *(ushort4*)&VbufT[((size_t)bh*EMB + tr + i)*SEQ + tbase + tc] = o;
    }
  }
}

// ---- flash: R7-proven structure + Pmask(R4) + fma/exp2 + zvec C-in + pointer-bump STAGE ----
__global__ __launch_bounds__(256, 4) void flash_kernel(
    const unsigned short* __restrict__ Qbuf, const unsigned short* __restrict__ Kbuf,
    const unsigned short* __restrict__ VbufT, const u32* __restrict__ Pmask,
    unsigned short* __restrict__ Oint)
{
  __shared__ alignas(16) char smem[40960];
  char* const K0 = smem;
  char* const K1 = smem + 8192;
  char* const V0 = smem + 16384;
  char* const V1 = smem + 24576;

  const int t = threadIdx.x;
  const int w = t >> 6, l = t & 63, g = l >> 4, q = l & 15;
  const int id = blockIdx.x;
  const int k_ = id >> 3;
  const int bh = (id & 7) * 4 + (k_ >> 5);   // XCD-aware: per-XCD K/V L2-resident
  const int qblk = k_ & 31;
  const int b = bh >> 3, h = bh & 7;

  // Q fragment (B-operand): lane holds Q[qrow=qblk*64+w*16+q][feat = 32kk+8g+j]
  short8 qf[2];
  {
    const unsigned short* qp = Qbuf + ((size_t)bh*SEQ + qblk*64 + w*16 + q)*EMB + g*8;
    qf[0] = *(const short8*)qp;
    qf[1] = *(const short8*)(qp + 32);
  }

  f32x4 oacc[4];
  #pragma unroll
  for (int c = 0; c < 4; ++c) oacc[c] = (f32x4){0.f,0.f,0.f,0.f};
  const f32x4 z4 = (f32x4){0.f,0.f,0.f,0.f};
  float lsum = 0.f;                          // row-sum for qrow = w*16 + q (replicated over g)

  char* const Pw = smem + 32768 + w*2048;    // wave-private P: 16 rows x 128B
  const int sw = (q & 7) << 4;

  const u32* mp = Pmask + ((size_t)(qblk*128 + w))*512 + l*8;

  // persistent staging pointers (next tile to stage); bumped once per STAGE
  const int unit0 = w*64 + l, unit1 = 256 + w*64 + l;
  const int row0 = unit0 >> 3, row1 = unit1 >> 3;
  const int gs0 = (unit0 & 7) ^ (row0 & 7), gs1 = (unit1 & 7) ^ (row1 & 7);
  const unsigned short* kp0 = Kbuf + ((size_t)bh*SEQ + row0)*EMB + gs0*8;
  const unsigned short* kp1 = Kbuf + ((size_t)bh*SEQ + row1)*EMB + gs1*8;
  const unsigned short* vp0 = VbufT + ((size_t)bh*EMB + row0)*SEQ + gs0*8;
  const unsigned short* vp1 = VbufT + ((size_t)bh*EMB + row1)*SEQ + gs1*8;

  #define STAGE(KDST, VDST) do {                                                      \
    gload16(kp0, (KDST) + (w*64)*16);                                                 \
    gload16(vp0, (VDST) + (w*64)*16);                                                 \
    gload16(kp1, (KDST) + (256 + w*64)*16);                                           \
    gload16(vp1, (VDST) + (256 + w*64)*16);                                           \
    kp0 += 64*EMB; kp1 += 64*EMB; vp0 += 64; vp1 += 64;                               \
  } while (0)

  STAGE(K0, V0);
  __syncthreads();

  // lane's S entries: sacc[c][r] = S[key = kt*64 + 16c + 4g + r][qrow = w*16 + q]
  #define TILE(kbase, vbase, DOSTAGE, nkdst, nvdst) do {                               \
    const uint4 mw0 = *(const uint4*)mp;                                               \
    const uint4 mw1 = *(const uint4*)(mp + 4);                                         \
    mp += 2048;                                                                        \
    f32x4 sacc[4];                                                                     \
    _Pragma("unroll") for (int c = 0; c < 4; ++c) {                                    \
      const short8 kf0 = *(const short8*)((kbase) + (16*c + q)*128 + ((g<<4) ^ sw));   \
      const short8 kf1 = *(const short8*)((kbase) + (16*c + q)*128 + (((4+g)<<4) ^ sw));\
      sacc[c] = __builtin_amdgcn_mfma_f32_16x16x32_bf16(kf0, qf[0], z4, 0,0,0);        \
      sacc[c] = __builtin_amdgcn_mfma_f32_16x16x32_bf16(kf1, qf[1], sacc[c], 0,0,0);   \
    }                                                                                  \
    u32 pw[8];                                                                         \
    _Pragma("unroll") for (int c = 0; c < 4; ++c) {                                    \
      const float p0 = vexp2(fmaf(sacc[c][0], LOG2E, NC0));                            \
      const float p1 = vexp2(fmaf(sacc[c][1], LOG2E, NC0));                            \
      const float p2 = vexp2(fmaf(sacc[c][2], LOG2E, NC0));                            \
      const float p3 = vexp2(fmaf(sacc[c][3], LOG2E, NC0));                            \
      pw[2*c]   = cvtpk(p0, p1);                                                       \
      pw[2*c+1] = cvtpk(p2, p3);                                                       \
    }                                                                                  \
    pw[0] &= mw0.x; pw[1] &= mw0.y; pw[2] &= mw0.z; pw[3] &= mw0.w;                    \
    pw[4] &= mw1.x; pw[5] &= mw1.y; pw[6] &= mw1.z; pw[7] &= mw1.w;                    \
    _Pragma("unroll") for (int c = 0; c < 4; ++c)                                      \
      *(uint2*)(Pw + ((q*128 + 32*c + 8*g) ^ sw)) = make_uint2(pw[2*c], pw[2*c+1]);    \
    /* register l-sum from the exact masked bf16 bits PV will consume (R4-proven) */   \
    float ts = 0.f;                                                                    \
    _Pragma("unroll") for (int i = 0; i < 8; ++i)                                      \
      ts += bits2f(pw[i] << 16) + bits2f(pw[i] & 0xFFFF0000u);                         \
    ts += __shfl_xor(ts, 16);                                                          \
    ts += __shfl_xor(ts, 32);                                                          \
    lsum += ts;                                                                        \
    __syncthreads();  /* P visible; prev K/V reads done */                             \
    if (DOSTAGE) { STAGE(nkdst, nvdst); }                                              \
    short8 pf[2];                                                                      \
    pf[0] = *(const short8*)(Pw + ((q*128 + 16*g) ^ sw));                              \
    pf[1] = *(const short8*)(Pw + ((q*128 + 64 + 16*g) ^ sw));                         \
    _Pragma("unroll") for (int c = 0; c < 4; ++c) {                                    \
      const short8 vf0 = *(const short8*)((vbase) + (16*c + q)*128 + ((g<<4) ^ sw));   \
      const short8 vf1 = *(const short8*)((vbase) + (16*c + q)*128 + (((4+g)<<4) ^ sw));\
      oacc[c] = __builtin_amdgcn_mfma_f32_16x16x32_bf16(pf[0], vf0, oacc[c], 0,0,0);   \
      oacc[c] = __builtin_amdgcn_mfma_f32_16x16x32_bf16(pf[1], vf1, oacc[c], 0,0,0);   \
    }                                                                                  \
    __syncthreads();                                                                   \
  } while (0)

  #pragma unroll 1
  for (int kt2 = 0; kt2 < 16; ++kt2) {
    TILE(K0, V0, true,       K1, V1);
    TILE(K1, V1, (kt2 < 15), K0, V0);
  }
  #undef TILE
  #undef STAGE

  // epilogue: oacc[c][r] = O[qrow = w*16 + 4g + r][feat = q + 16c]; lsum at lane (g, qrow&15)
  #pragma unroll
  for (int r = 0; r < 4; ++r) {
    const float lr = __shfl(lsum, (l & 48) | (4*g + r));
    const float inv = (lr > 1e-30f) ? 1.f / lr : 0.f;
    #pragma unroll
    for (int c = 0; c < 4; ++c) {
      Oint[((size_t)b*SEQ + qblk*64 + w*16 + 4*g + r)*(EMB*HEADS) + h*EMB + q + 16*c] =
          f2bf(oacc[c][r] * inv);
    }
  }
}

// ---- output projection: bf16 [8192,512] @ fp32 [512,64] + bu, 512 blocks x 16 rows ----
__global__ __launch_bounds__(256) void outproj_kernel(
    const unsigned short* __restrict__ Oint, const float* __restrict__ Wu,
    const float* __restrict__ bu, float* __restrict__ out)
{
  __shared__ alignas(16) unsigned short Os[16][520];
  const int t = threadIdx.x;
  const int rb = blockIdx.x;       // 0..511

  #pragma unroll
  for (int u = 0; u < 4; ++u) {
    const int chunk = t + u*256;           // 1024 chunks of 8 bf16
    const int row = chunk >> 6, col8 = (chunk & 63) * 8;
    *(short8*)&Os[row][col8] =
        *(const short8*)&Oint[((size_t)(rb*16 + row))*(EMB*HEADS) + col8];
  }
  __syncthreads();

  const int rr = t >> 4;           // row 0..15
  const int cg = t & 15;           // col group (4 cols)
  float4 acc = {0,0,0,0};
  #pragma unroll 1
  for (int k8 = 0; k8 < 64; ++k8) {
    const short8 a8 = *(const short8*)&Os[rr][k8*8];
    #pragma unroll
    for (int j = 0; j < 8; ++j) {
      const float a = bf2f((unsigned short)a8[j]);
      acc = fmad4(ld4(&Wu[(size_t)(k8*8 + j)*EMB + cg*4]), a, acc);
    }
  }
  const float4 bv = ld4(&bu[cg*4]);
  acc.x += bv.x; acc.y += bv.y; acc.z += bv.z; acc.w += bv.w;
  *(float4*)&out[(size_t)(rb*16 + rr)*EMB + cg*4] = acc;
}

extern "C" void kernel_launch(void* const* d_in, const int* in_sizes, int n_in,
                              void* d_out, int out_size, void* d_ws, size_t ws_size,
                              hipStream_t stream) {
  const float* x   = (const float*)d_in[0];
  const float* y   = (const float*)d_in[1];
  const int*   mask= (const int*)d_in[2];
  const float* Wk  = (const float*)d_in[3];
  const float* Wq  = (const float*)d_in[4];
  const float* Wv  = (const float*)d_in[5];
  const float* Wu  = (const float*)d_in[6];
  const float* bu  = (const float*)d_in[7];
  float* out = (float*)d_out;

  // ws: Qbuf(8M) | Kbuf(8M) | VbufT(8M) | Pmask(8M) | Oint bf16(8M) = 40 MiB (R4-proven)
  unsigned short* Qbuf  = (unsigned short*)d_ws;
  unsigned short* Kbuf  = Qbuf + (size_t)32*SEQ*EMB;
  unsigned short* VbufT = Kbuf + (size_t)32*SEQ*EMB;
  u32* Pmask = (u32*)((char*)d_ws + (size_t)24*1024*1024);
  unsigned short* Oint = (unsigned short*)((char*)d_ws + (size_t)32*1024*1024);

  packmask_kernel<<<8192, 256, 0, stream>>>(mask, Pmask);
  proj_kernel<<<dim3(128, 8, 3), 256, 0, stream>>>(x, y, Wk, Wq, Wv, Kbuf, Qbuf, VbufT);
  flash_kernel<<<1024, 256, 0, stream>>>(Qbuf, Kbuf, VbufT, Pmask, Oint);
  outproj_kernel<<<512, 256, 0, stream>>>(Oint, Wu, bu, out);
}

// Round 9
// 124.398 us; speedup vs baseline: 1.0663x; 1.0083x over previous
//
#include <hip/hip_runtime.h>

#define EMB 64
#define HEADS 8
#define SEQ 2048
#define LSF 68

typedef short short8 __attribute__((ext_vector_type(8)));
typedef float f32x4 __attribute__((ext_vector_type(4)));
typedef unsigned int u32;

__device__ __forceinline__ float4 ld4(const float* p) { return *(const float4*)p; }
__device__ __forceinline__ float4 fmad4(float4 a, float s, float4 c) {
  c.x += a.x*s; c.y += a.y*s; c.z += a.z*s; c.w += a.w*s; return c;
}
__device__ __forceinline__ unsigned short f2bf(float f) {
  union { float f; unsigned u; } x; x.f = f;
  return (unsigned short)((x.u + 0x7fffu + ((x.u >> 16) & 1u)) >> 16);
}
__device__ __forceinline__ float bf2f(unsigned short s) {
  union { unsigned u; float f; } x; x.u = ((unsigned)s) << 16;
  return x.f;
}
__device__ __forceinline__ float bits2f(u32 u) {
  union { u32 u; float f; } x; x.u = u;
  return x.f;
}
__device__ __forceinline__ u32 cvtpk(float lo, float hi) {
  u32 r;
  asm("v_cvt_pk_bf16_f32 %0, %1, %2" : "=v"(r) : "v"(lo), "v"(hi));
  return r;
}
__device__ __forceinline__ float vexp2(float x) {
  float r;
  asm("v_exp_f32 %0, %1" : "=v"(r) : "v"(x));
  return r;
}
__device__ __forceinline__ void gload16(const void* g, void* l) {
  __builtin_amdgcn_global_load_lds((const __attribute__((address_space(1))) unsigned int*)g,
                                   (__attribute__((address_space(3))) unsigned int*)l, 16, 0, 0);
}

#define LOG2E 1.4426950408889634f
#define NC0  (-5.770780163555854f)   /* -4 * log2(e) */

// ---- fused prep: z=0 K proj, z=1 V^T proj, z=2 Q proj, z=3 mask pack ----
// mask word gid = ((qblk*32 + kt)*4 + w)*512 + l*8 + i covers keys (k,k+1) for
// q = qblk*64 + 16*(i>>1) + (l&15), key k = kt*64 + w*16 + 4*(l>>4) + 2*(i&1)
__global__ __launch_bounds__(256) void prep_kernel(
    const float* __restrict__ x, const float* __restrict__ y,
    const float* __restrict__ Wk, const float* __restrict__ Wq, const float* __restrict__ Wv,
    const int* __restrict__ mask,
    unsigned short* __restrict__ Kbuf, unsigned short* __restrict__ Qbuf,
    unsigned short* __restrict__ VbufT, u32* __restrict__ pmask)
{
  __shared__ float As[64][LSF];
  __shared__ float Bs[64][LSF];
  const int t = threadIdx.x;
  const int z = blockIdx.z;        // 0:K 1:V^T 2:Q 3:maskpack

  if (z == 3) {
    const int bid = blockIdx.x * 8 + blockIdx.y;     // 0..1023
    #pragma unroll
    for (int it = 0; it < 8; ++it) {
      const int gid = bid * 2048 + it * 256 + t;     // 2M words
      const int i = gid & 7, ll = (gid >> 3) & 63, ww = (gid >> 9) & 3;
      const int kt = (gid >> 11) & 31, qblk = gid >> 16;
      const int qq = qblk*64 + 16*(i >> 1) + (ll & 15);
      const int kk = kt*64 + ww*16 + 4*(ll >> 4) + 2*(i & 1);
      const int2 mm = *(const int2*)&mask[(size_t)qq * SEQ + kk];
      pmask[gid] = (mm.x ? 0xFFFFu : 0u) | (mm.y ? 0xFFFF0000u : 0u);
    }
    return;
  }

  const int rowblk = blockIdx.x;   // 0..127 over B*T/64
  const int h = blockIdx.y;        // 0..7
  const float* __restrict__ in = (z == 2) ? y : x;
  const float* __restrict__ W = (z == 0) ? Wk : (z == 1) ? Wv : Wq;

  for (int i = t; i < 1024; i += 256) {
    const int r = i >> 4, c4 = (i & 15) << 2;
    *(float4*)&As[r][c4] = ld4(&in[(size_t)(rowblk*64 + r)*EMB + c4]);
    *(float4*)&Bs[r][c4] = ld4(&W[(size_t)r*(EMB*HEADS) + h*EMB + c4]);
  }
  __syncthreads();

  const int tr = (t >> 4) << 2;
  const int tc = (t & 15) << 2;
  float4 acc[4];
  #pragma unroll
  for (int i = 0; i < 4; ++i) acc[i] = (float4){0,0,0,0};
  #pragma unroll 8
  for (int k = 0; k < 64; ++k) {
    const float4 w = *(const float4*)&Bs[k][tc];
    #pragma unroll
    for (int i = 0; i < 4; ++i) acc[i] = fmad4(w, As[tr+i][k], acc[i]);
  }

  const int b = rowblk >> 5;
  const int tbase = (rowblk & 31) * 64;
  const int bh = b * HEADS + h;
  const float scale = (z == 2) ? 0.125f : 1.0f;

  if (z != 1) {
    unsigned short* __restrict__ dst = (z == 0) ? Kbuf : Qbuf;
    #pragma unroll
    for (int i = 0; i < 4; ++i) {
      ushort4 o;
      o.x = f2bf(acc[i].x * scale); o.y = f2bf(acc[i].y * scale);
      o.z = f2bf(acc[i].z * scale); o.w = f2bf(acc[i].w * scale);
      *(ushort4*)&dst[((size_t)bh*SEQ + tbase + tr + i)*EMB + tc] = o;
    }
  } else {
    __syncthreads();
    #pragma unroll
    for (int i = 0; i < 4; ++i) {
      As[tc+0][tr+i] = acc[i].x; As[tc+1][tr+i] = acc[i].y;
      As[tc+2][tr+i] = acc[i].z; As[tc+3][tr+i] = acc[i].w;
    }
    __syncthreads();
    #pragma unroll
    for (int i = 0; i < 4; ++i) {   // row tr+i = feature
      ushort4 o;
      o.x = f2bf(As[tr+i][tc+0]); o.y = f2bf(As[tr+i][tc+1]);
      o.z = f2bf(As[tr+i][tc+2]); o.w = f2bf(As[tr+i][tc+3]);
      *(ushort4*)&VbufT[((size_t)bh*EMB + tr + i)*SEQ + tbase + tc] = o;
    }
  }
}

// ---- flash: key-quarter QK^T (Q all-rows in regs), shared P_lds, 2x2-split PV ----
__global__ __launch_bounds__(256, 4) void flash_kernel(
    const unsigned short* __restrict__ Qbuf, const unsigned short* __restrict__ Kbuf,
    const unsigned short* __restrict__ VbufT, const u32* __restrict__ Pmask,
    unsigned short* __restrict__ Oint)
{
  __shared__ alignas(16) char smem[40960];
  char* const K0 = smem;
  char* const K1 = smem + 8192;
  char* const V0 = smem + 16384;
  char* const V1 = smem + 24576;
  char* const P_lds = smem + 32768;          // block-shared P': 64 q rows x 128B (64 keys)

  const int t = threadIdx.x;
  const int w = t >> 6, l = t & 63, g = l >> 4, q15 = l & 15;
  const int hw = w >> 1, fw = w & 1;         // PV: q-half / feat-half ownership
  const int id = blockIdx.x;
  const int k_ = id >> 3;
  const int bh = (id & 7) * 4 + (k_ >> 5);   // XCD-aware: per-XCD K/V L2-resident
  const int qblk = k_ & 31;
  const int b = bh >> 3, h = bh & 7;
  const int sw = (q15 & 7) << 4;

  // Q B-frags for ALL 64 q-rows: qf[c][kk] = Q[qblk*64 + 16c + q15][32kk + 8g + j]
  short8 qf[4][2];
  #pragma unroll
  for (int c = 0; c < 4; ++c) {
    const unsigned short* qp = Qbuf + ((size_t)bh*SEQ + qblk*64 + 16*c + q15)*EMB + g*8;
    qf[c][0] = *(const short8*)qp;
    qf[c][1] = *(const short8*)(qp + 32);
  }

  f32x4 oacc[2][2];                          // O[q = hw*32+16c2+4g+r][feat = fw*32+16cf+q15]
  #pragma unroll
  for (int c2 = 0; c2 < 2; ++c2)
    #pragma unroll
    for (int cf = 0; cf < 2; ++cf) oacc[c2][cf] = (f32x4){0.f,0.f,0.f,0.f};
  const f32x4 z4 = (f32x4){0.f,0.f,0.f,0.f};
  float lsum[4] = {0.f,0.f,0.f,0.f};         // key-quarter-w partial l for q = 16c + q15

  const u32* mp = Pmask + ((size_t)(qblk*128 + w))*512 + l*8;

  const int unit0 = w*64 + l, unit1 = 256 + w*64 + l;
  const int row0 = unit0 >> 3, row1 = unit1 >> 3;
  const int gs0 = (unit0 & 7) ^ (row0 & 7), gs1 = (unit1 & 7) ^ (row1 & 7);
  const unsigned short* kp0 = Kbuf + ((size_t)bh*SEQ + row0)*EMB + gs0*8;
  const unsigned short* kp1 = Kbuf + ((size_t)bh*SEQ + row1)*EMB + gs1*8;
  const unsigned short* vp0 = VbufT + ((size_t)bh*EMB + row0)*SEQ + gs0*8;
  const unsigned short* vp1 = VbufT + ((size_t)bh*EMB + row1)*SEQ + gs1*8;

  #define STAGE(KDST, VDST) do {                                                      \
    gload16(kp0, (KDST) + (w*64)*16);                                                 \
    gload16(vp0, (VDST) + (w*64)*16);                                                 \
    gload16(kp1, (KDST) + (256 + w*64)*16);                                           \
    gload16(vp1, (VDST) + (256 + w*64)*16);                                           \
    kp0 += 64*EMB; kp1 += 64*EMB; vp0 += 64; vp1 += 64;                               \
  } while (0)

  STAGE(K0, V0);
  __syncthreads();

  // QK: sacc[c][r] = S[key = w*16 + 4g + r][q = 16c + q15]
  #define TILE(kbase, vbase, DOSTAGE, nkdst, nvdst) do {                               \
    const uint4 mw0 = *(const uint4*)mp;                                               \
    const uint4 mw1 = *(const uint4*)(mp + 4);                                         \
    mp += 2048;                                                                        \
    const short8 kf0 = *(const short8*)((kbase) + (w*16 + q15)*128 + ((g<<4) ^ sw));   \
    const short8 kf1 = *(const short8*)((kbase) + (w*16 + q15)*128 + (((4+g)<<4) ^ sw));\
    f32x4 sacc[4];                                                                     \
    _Pragma("unroll") for (int c = 0; c < 4; ++c) {                                    \
      sacc[c] = __builtin_amdgcn_mfma_f32_16x16x32_bf16(kf0, qf[c][0], z4, 0,0,0);     \
      sacc[c] = __builtin_amdgcn_mfma_f32_16x16x32_bf16(kf1, qf[c][1], sacc[c], 0,0,0);\
    }                                                                                  \
    u32 pw[8];                                                                         \
    _Pragma("unroll") for (int c = 0; c < 4; ++c) {                                    \
      const float p0 = vexp2(fmaf(sacc[c][0], LOG2E, NC0));                            \
      const float p1 = vexp2(fmaf(sacc[c][1], LOG2E, NC0));                            \
      const float p2 = vexp2(fmaf(sacc[c][2], LOG2E, NC0));                            \
      const float p3 = vexp2(fmaf(sacc[c][3], LOG2E, NC0));                            \
      pw[2*c]   = cvtpk(p0, p1);                                                       \
      pw[2*c+1] = cvtpk(p2, p3);                                                       \
    }                                                                                  \
    pw[0] &= mw0.x; pw[1] &= mw0.y; pw[2] &= mw0.z; pw[3] &= mw0.w;                    \
    pw[4] &= mw1.x; pw[5] &= mw1.y; pw[6] &= mw1.z; pw[7] &= mw1.w;                    \
    _Pragma("unroll") for (int c = 0; c < 4; ++c) {                                    \
      *(uint2*)(P_lds + (16*c + q15)*128 + ((w*32 + 8*g) ^ sw)) =                      \
          make_uint2(pw[2*c], pw[2*c+1]);                                              \
      float ts = bits2f(pw[2*c] << 16) + bits2f(pw[2*c] & 0xFFFF0000u)                 \
               + bits2f(pw[2*c+1] << 16) + bits2f(pw[2*c+1] & 0xFFFF0000u);            \
      ts += __shfl_xor(ts, 16);                                                        \
      ts += __shfl_xor(ts, 32);                                                        \
      lsum[c] += ts;                                                                   \
    }                                                                                  \
    __syncthreads();  /* P_lds complete (all waves); prev K/V reads done */            \
    if (DOSTAGE) { STAGE(nkdst, nvdst); }                                              \
    short8 pf[2][2], vf[2][2];                                                         \
    _Pragma("unroll") for (int c2 = 0; c2 < 2; ++c2) {                                 \
      pf[c2][0] = *(const short8*)(P_lds + (hw*32 + 16*c2 + q15)*128 + ((g<<4) ^ sw)); \
      pf[c2][1] = *(const short8*)(P_lds + (hw*32 + 16*c2 + q15)*128 + (((4+g)<<4) ^ sw)); \
    }                                                                                  \
    _Pragma("unroll") for (int cf = 0; cf < 2; ++cf) {                                 \
      vf[cf][0] = *(const short8*)((vbase) + (fw*32 + 16*cf + q15)*128 + ((g<<4) ^ sw)); \
      vf[cf][1] = *(const short8*)((vbase) + (fw*32 + 16*cf + q15)*128 + (((4+g)<<4) ^ sw)); \
    }                                                                                  \
    _Pragma("unroll") for (int c2 = 0; c2 < 2; ++c2)                                   \
      _Pragma("unroll") for (int cf = 0; cf < 2; ++cf) {                               \
        oacc[c2][cf] = __builtin_amdgcn_mfma_f32_16x16x32_bf16(pf[c2][0], vf[cf][0],   \
                                                               oacc[c2][cf], 0,0,0);   \
        oacc[c2][cf] = __builtin_amdgcn_mfma_f32_16x16x32_bf16(pf[c2][1], vf[cf][1],   \
                                                               oacc[c2][cf], 0,0,0);   \
      }                                                                                \
    __syncthreads();                                                                   \
  } while (0)

  #pragma unroll 1
  for (int kt2 = 0; kt2 < 16; ++kt2) {
    TILE(K0, V0, true,       K1, V1);
    TILE(K1, V1, (kt2 < 15), K0, V0);
  }
  #undef TILE
  #undef STAGE

  // epilogue: cross-wave l reduction through retired K0 region
  float* const Lred = (float*)smem;          // [w][q] : 4 x 64 floats
  if (g == 0) {
    #pragma unroll
    for (int c = 0; c < 4; ++c) Lred[w*64 + 16*c + q15] = lsum[c];
  }
  __syncthreads();
  #pragma unroll
  for (int c2 = 0; c2 < 2; ++c2) {
    const int qi = hw*32 + 16*c2 + q15;
    const float ltot = Lred[qi] + Lred[64 + qi] + Lred[128 + qi] + Lred[192 + qi];
    #pragma unroll
    for (int r = 0; r < 4; ++r) {
      const float lr = __shfl(ltot, (l & 48) | (4*g + r));
      const float inv = (lr > 1e-30f) ? 1.f / lr : 0.f;
      #pragma unroll
      for (int cf = 0; cf < 2; ++cf) {
        Oint[((size_t)b*SEQ + qblk*64 + hw*32 + 16*c2 + 4*g + r)*(EMB*HEADS)
             + h*EMB + fw*32 + 16*cf + q15] = f2bf(oacc[c2][cf][r] * inv);
      }
    }
  }
}

// ---- output projection: bf16 [8192,512] @ fp32 [512,64] + bu, 512 blocks x 16 rows ----
__global__ __launch_bounds__(256) void outproj_kernel(
    const unsigned short* __restrict__ Oint, const float* __restrict__ Wu,
    const float* __restrict__ bu, float* __restrict__ out)
{
  __shared__ alignas(16) unsigned short Os[16][520];
  const int t = threadIdx.x;
  const int rb = blockIdx.x;       // 0..511

  #pragma unroll
  for (int u = 0; u < 4; ++u) {
    const int chunk = t + u*256;           // 1024 chunks of 8 bf16
    const int row = chunk >> 6, col8 = (chunk & 63) * 8;
    *(short8*)&Os[row][col8] =
        *(const short8*)&Oint[((size_t)(rb*16 + row))*(EMB*HEADS) + col8];
  }
  __syncthreads();

  const int rr = t >> 4;           // row 0..15
  const int cg = t & 15;           // col group (4 cols)
  float4 acc = {0,0,0,0};
  #pragma unroll 1
  for (int k8 = 0; k8 < 64; ++k8) {
    const short8 a8 = *(const short8*)&Os[rr][k8*8];
    #pragma unroll
    for (int j = 0; j < 8; ++j) {
      const float a = bf2f((unsigned short)a8[j]);
      acc = fmad4(ld4(&Wu[(size_t)(k8*8 + j)*EMB + cg*4]), a, acc);
    }
  }
  const float4 bv = ld4(&bu[cg*4]);
  acc.x += bv.x; acc.y += bv.y; acc.z += bv.z; acc.w += bv.w;
  *(float4*)&out[(size_t)(rb*16 + rr)*EMB + cg*4] = acc;
}

extern "C" void kernel_launch(void* const* d_in, const int* in_sizes, int n_in,
                              void* d_out, int out_size, void* d_ws, size_t ws_size,
                              hipStream_t stream) {
  const float* x   = (const float*)d_in[0];
  const float* y   = (const float*)d_in[1];
  const int*   mask= (const int*)d_in[2];
  const float* Wk  = (const float*)d_in[3];
  const float* Wq  = (const float*)d_in[4];
  const float* Wv  = (const float*)d_in[5];
  const float* Wu  = (const float*)d_in[6];
  const float* bu  = (const float*)d_in[7];
  float* out = (float*)d_out;

  // ws: Qbuf(8M) | Kbuf(8M) | VbufT(8M) | Pmask(8M) | Oint bf16(8M) = 40 MiB
  unsigned short* Qbuf  = (unsigned short*)d_ws;
  unsigned short* Kbuf  = Qbuf + (size_t)32*SEQ*EMB;
  unsigned short* VbufT = Kbuf + (size_t)32*SEQ*EMB;
  u32* Pmask = (u32*)((char*)d_ws + (size_t)24*1024*1024);
  unsigned short* Oint = (unsigned short*)((char*)d_ws + (size_t)32*1024*1024);

  prep_kernel<<<dim3(128, 8, 4), 256, 0, stream>>>(x, y, Wk, Wq, Wv, mask,
                                                   Kbuf, Qbuf, VbufT, Pmask);
  flash_kernel<<<1024, 256, 0, stream>>>(Qbuf, Kbuf, VbufT, Pmask, Oint);
  outproj_kernel<<<512, 256, 0, stream>>>(Oint, Wu, bu, out);
}

// Round 10
// 101.538 us; speedup vs baseline: 1.3064x; 1.2251x over previous
//
#include <hip/hip_runtime.h>

#define EMB 64
#define HEADS 8
#define SEQ 2048
#define LSF 68

typedef short short8 __attribute__((ext_vector_type(8)));
typedef float f32x4 __attribute__((ext_vector_type(4)));
typedef unsigned int u32;

__device__ __forceinline__ float4 ld4(const float* p) { return *(const float4*)p; }
__device__ __forceinline__ float4 fmad4(float4 a, float s, float4 c) {
  c.x += a.x*s; c.y += a.y*s; c.z += a.z*s; c.w += a.w*s; return c;
}
__device__ __forceinline__ unsigned short f2bf(float f) {
  union { float f; unsigned u; } x; x.f = f;
  return (unsigned short)((x.u + 0x7fffu + ((x.u >> 16) & 1u)) >> 16);
}
__device__ __forceinline__ float bf2f(unsigned short s) {
  union { unsigned u; float f; } x; x.u = ((unsigned)s) << 16;
  return x.f;
}
__device__ __forceinline__ float bits2f(u32 u) {
  union { u32 u; float f; } x; x.u = u;
  return x.f;
}
__device__ __forceinline__ u32 cvtpk(float lo, float hi) {
  u32 r;
  asm("v_cvt_pk_bf16_f32 %0, %1, %2" : "=v"(r) : "v"(lo), "v"(hi));
  return r;
}
__device__ __forceinline__ float vexp2(float x) {
  float r;
  asm("v_exp_f32 %0, %1" : "=v"(r) : "v"(x));
  return r;
}
__device__ __forceinline__ void gload16(const void* g, void* l) {
  __builtin_amdgcn_global_load_lds((const __attribute__((address_space(1))) unsigned int*)g,
                                   (__attribute__((address_space(3))) unsigned int*)l, 16, 0, 0);
}

#define LOG2E 1.4426950408889634f
#define NC0  (-5.770780163555854f)   /* -4 * log2(e) */

// ---- fused prep: z=0 K proj, z=1 V^T proj, z=2 Q proj, z=3 mask pack (R8 layout) + WuT ----
__global__ __launch_bounds__(256) void prep_kernel(
    const float* __restrict__ x, const float* __restrict__ y,
    const float* __restrict__ Wk, const float* __restrict__ Wq, const float* __restrict__ Wv,
    const int* __restrict__ mask, const float* __restrict__ Wu,
    unsigned short* __restrict__ Kbuf, unsigned short* __restrict__ Qbuf,
    unsigned short* __restrict__ VbufT, u32* __restrict__ pmask,
    unsigned short* __restrict__ WuThi, unsigned short* __restrict__ WuTlo)
{
  __shared__ float As[64][LSF];
  __shared__ float Bs[64][LSF];
  const int t = threadIdx.x;
  const int z = blockIdx.z;        // 0:K 1:V^T 2:Q 3:maskpack(+WuT)

  if (z == 3) {
    const int bid = blockIdx.x * 8 + blockIdx.y;     // 0..1023
    #pragma unroll
    for (int it = 0; it < 8; ++it) {
      // R8-proven packmask indexing (matched pair with R8 flash):
      // q = qblk*64 + w*16 + (l&15); k = kt*64 + 16c + 4g + 2rr
      const int gid = bid * 2048 + it * 256 + t;     // 2M words
      const int i = gid & 7, ll = (gid >> 3) & 63, ww = (gid >> 9) & 3;
      const int kt = (gid >> 11) & 31, qblk = gid >> 16;
      const int qq = qblk*64 + ww*16 + (ll & 15);
      const int g = ll >> 4, c = i >> 1, rr = i & 1;
      const int kk = kt*64 + 16*c + 4*g + 2*rr;
      const int2 mm = *(const int2*)&mask[(size_t)qq * SEQ + kk];
      pmask[gid] = (mm.x ? 0xFFFFu : 0u) | (mm.y ? 0xFFFF0000u : 0u);
    }
    if (blockIdx.y == 7) {
      // WuT split-precision: WuT[n][k] = Wu[k][n] as hi + lo bf16 planes
      const int idx = blockIdx.x * 256 + t;          // 0..32767
      const int k = idx >> 6, n = idx & 63;
      const float wv = Wu[(size_t)k * EMB + n];
      const unsigned short hi = f2bf(wv);
      const unsigned short lo = f2bf(wv - bf2f(hi));
      WuThi[(size_t)n * 512 + k] = hi;
      WuTlo[(size_t)n * 512 + k] = lo;
    }
    return;
  }

  const int rowblk = blockIdx.x;   // 0..127 over B*T/64
  const int h = blockIdx.y;        // 0..7
  const float* __restrict__ in = (z == 2) ? y : x;
  const float* __restrict__ W = (z == 0) ? Wk : (z == 1) ? Wv : Wq;

  for (int i = t; i < 1024; i += 256) {
    const int r = i >> 4, c4 = (i & 15) << 2;
    *(float4*)&As[r][c4] = ld4(&in[(size_t)(rowblk*64 + r)*EMB + c4]);
    *(float4*)&Bs[r][c4] = ld4(&W[(size_t)r*(EMB*HEADS) + h*EMB + c4]);
  }
  __syncthreads();

  const int tr = (t >> 4) << 2;
  const int tc = (t & 15) << 2;
  float4 acc[4];
  #pragma unroll
  for (int i = 0; i < 4; ++i) acc[i] = (float4){0,0,0,0};
  #pragma unroll 8
  for (int k = 0; k < 64; ++k) {
    const float4 w = *(const float4*)&Bs[k][tc];
    #pragma unroll
    for (int i = 0; i < 4; ++i) acc[i] = fmad4(w, As[tr+i][k], acc[i]);
  }

  const int b = rowblk >> 5;
  const int tbase = (rowblk & 31) * 64;
  const int bh = b * HEADS + h;
  const float scale = (z == 2) ? 0.125f : 1.0f;

  if (z != 1) {
    unsigned short* __restrict__ dst = (z == 0) ? Kbuf : Qbuf;
    #pragma unroll
    for (int i = 0; i < 4; ++i) {
      ushort4 o;
      o.x = f2bf(acc[i].x * scale); o.y = f2bf(acc[i].y * scale);
      o.z = f2bf(acc[i].z * scale); o.w = f2bf(acc[i].w * scale);
      *(ushort4*)&dst[((size_t)bh*SEQ + tbase + tr + i)*EMB + tc] = o;
    }
  } else {
    __syncthreads();
    #pragma unroll
    for (int i = 0; i < 4; ++i) {
      As[tc+0][tr+i] = acc[i].x; As[tc+1][tr+i] = acc[i].y;
      As[tc+2][tr+i] = acc[i].z; As[tc+3][tr+i] = acc[i].w;
    }
    __syncthreads();
    #pragma unroll
    for (int i = 0; i < 4; ++i) {   // row tr+i = feature
      ushort4 o;
      o.x = f2bf(As[tr+i][tc+0]); o.y = f2bf(As[tr+i][tc+1]);
      o.z = f2bf(As[tr+i][tc+2]); o.w = f2bf(As[tr+i][tc+3]);
      *(ushort4*)&VbufT[((size_t)bh*EMB + tr + i)*SEQ + tbase + tc] = o;
    }
  }
}

// ---- flash: R8-proven verbatim (wave-private P, Pmask AND, register l-sum) ----
__global__ __launch_bounds__(256, 4) void flash_kernel(
    const unsigned short* __restrict__ Qbuf, const unsigned short* __restrict__ Kbuf,
    const unsigned short* __restrict__ VbufT, const u32* __restrict__ Pmask,
    unsigned short* __restrict__ Oint)
{
  __shared__ alignas(16) char smem[40960];
  char* const K0 = smem;
  char* const K1 = smem + 8192;
  char* const V0 = smem + 16384;
  char* const V1 = smem + 24576;

  const int t = threadIdx.x;
  const int w = t >> 6, l = t & 63, g = l >> 4, q = l & 15;
  const int id = blockIdx.x;
  const int k_ = id >> 3;
  const int bh = (id & 7) * 4 + (k_ >> 5);   // XCD-aware: per-XCD K/V L2-resident
  const int qblk = k_ & 31;
  const int b = bh >> 3, h = bh & 7;

  short8 qf[2];
  {
    const unsigned short* qp = Qbuf + ((size_t)bh*SEQ + qblk*64 + w*16 + q)*EMB + g*8;
    qf[0] = *(const short8*)qp;
    qf[1] = *(const short8*)(qp + 32);
  }

  f32x4 oacc[4];
  #pragma unroll
  for (int c = 0; c < 4; ++c) oacc[c] = (f32x4){0.f,0.f,0.f,0.f};
  const f32x4 z4 = (f32x4){0.f,0.f,0.f,0.f};
  float lsum = 0.f;

  char* const Pw = smem + 32768 + w*2048;    // wave-private P: 16 rows x 128B
  const int sw = (q & 7) << 4;

  const u32* mp = Pmask + ((size_t)(qblk*128 + w))*512 + l*8;

  const int unit0 = w*64 + l, unit1 = 256 + w*64 + l;
  const int row0 = unit0 >> 3, row1 = unit1 >> 3;
  const int gs0 = (unit0 & 7) ^ (row0 & 7), gs1 = (unit1 & 7) ^ (row1 & 7);
  const unsigned short* kp0 = Kbuf + ((size_t)bh*SEQ + row0)*EMB + gs0*8;
  const unsigned short* kp1 = Kbuf + ((size_t)bh*SEQ + row1)*EMB + gs1*8;
  const unsigned short* vp0 = VbufT + ((size_t)bh*EMB + row0)*SEQ + gs0*8;
  const unsigned short* vp1 = VbufT + ((size_t)bh*EMB + row1)*SEQ + gs1*8;

  #define STAGE(KDST, VDST) do {                                                      \
    gload16(kp0, (KDST) + (w*64)*16);                                                 \
    gload16(vp0, (VDST) + (w*64)*16);                                                 \
    gload16(kp1, (KDST) + (256 + w*64)*16);                                           \
    gload16(vp1, (VDST) + (256 + w*64)*16);                                           \
    kp0 += 64*EMB; kp1 += 64*EMB; vp0 += 64; vp1 += 64;                               \
  } while (0)

  STAGE(K0, V0);
  __syncthreads();

  #define TILE(kbase, vbase, DOSTAGE, nkdst, nvdst) do {                               \
    const uint4 mw0 = *(const uint4*)mp;                                               \
    const uint4 mw1 = *(const uint4*)(mp + 4);                                         \
    mp += 2048;                                                                        \
    f32x4 sacc[4];                                                                     \
    _Pragma("unroll") for (int c = 0; c < 4; ++c) {                                    \
      const short8 kf0 = *(const short8*)((kbase) + (16*c + q)*128 + ((g<<4) ^ sw));   \
      const short8 kf1 = *(const short8*)((kbase) + (16*c + q)*128 + (((4+g)<<4) ^ sw));\
      sacc[c] = __builtin_amdgcn_mfma_f32_16x16x32_bf16(kf0, qf[0], z4, 0,0,0);        \
      sacc[c] = __builtin_amdgcn_mfma_f32_16x16x32_bf16(kf1, qf[1], sacc[c], 0,0,0);   \
    }                                                                                  \
    u32 pw[8];                                                                         \
    _Pragma("unroll") for (int c = 0; c < 4; ++c) {                                    \
      const float p0 = vexp2(fmaf(sacc[c][0], LOG2E, NC0));                            \
      const float p1 = vexp2(fmaf(sacc[c][1], LOG2E, NC0));                            \
      const float p2 = vexp2(fmaf(sacc[c][2], LOG2E, NC0));                            \
      const float p3 = vexp2(fmaf(sacc[c][3], LOG2E, NC0));                            \
      pw[2*c]   = cvtpk(p0, p1);                                                       \
      pw[2*c+1] = cvtpk(p2, p3);                                                       \
    }                                                                                  \
    pw[0] &= mw0.x; pw[1] &= mw0.y; pw[2] &= mw0.z; pw[3] &= mw0.w;                    \
    pw[4] &= mw1.x; pw[5] &= mw1.y; pw[6] &= mw1.z; pw[7] &= mw1.w;                    \
    _Pragma("unroll") for (int c = 0; c < 4; ++c)                                      \
      *(uint2*)(Pw + ((q*128 + 32*c + 8*g) ^ sw)) = make_uint2(pw[2*c], pw[2*c+1]);    \
    float ts = 0.f;                                                                    \
    _Pragma("unroll") for (int i = 0; i < 8; ++i)                                      \
      ts += bits2f(pw[i] << 16) + bits2f(pw[i] & 0xFFFF0000u);                         \
    ts += __shfl_xor(ts, 16);                                                          \
    ts += __shfl_xor(ts, 32);                                                          \
    lsum += ts;                                                                        \
    __syncthreads();  /* P visible; prev K/V reads done */                             \
    if (DOSTAGE) { STAGE(nkdst, nvdst); }                                              \
    short8 pf[2];                                                                      \
    pf[0] = *(const short8*)(Pw + ((q*128 + 16*g) ^ sw));                              \
    pf[1] = *(const short8*)(Pw + ((q*128 + 64 + 16*g) ^ sw));                         \
    _Pragma("unroll") for (int c = 0; c < 4; ++c) {                                    \
      const short8 vf0 = *(const short8*)((vbase) + (16*c + q)*128 + ((g<<4) ^ sw));   \
      const short8 vf1 = *(const short8*)((vbase) + (16*c + q)*128 + (((4+g)<<4) ^ sw));\
      oacc[c] = __builtin_amdgcn_mfma_f32_16x16x32_bf16(pf[0], vf0, oacc[c], 0,0,0);   \
      oacc[c] = __builtin_amdgcn_mfma_f32_16x16x32_bf16(pf[1], vf1, oacc[c], 0,0,0);   \
    }                                                                                  \
    __syncthreads();                                                                   \
  } while (0)

  #pragma unroll 1
  for (int kt2 = 0; kt2 < 16; ++kt2) {
    TILE(K0, V0, true,       K1, V1);
    TILE(K1, V1, (kt2 < 15), K0, V0);
  }
  #undef TILE
  #undef STAGE

  #pragma unroll
  for (int r = 0; r < 4; ++r) {
    const float lr = __shfl(lsum, (l & 48) | (4*g + r));
    const float inv = (lr > 1e-30f) ? 1.f / lr : 0.f;
    #pragma unroll
    for (int c = 0; c < 4; ++c) {
      Oint[((size_t)b*SEQ + qblk*64 + w*16 + 4*g + r)*(EMB*HEADS) + h*EMB + q + 16*c] =
          f2bf(oacc[c][r] * inv);
    }
  }
}

// ---- output projection via MFMA: out = Oint(bf16) @ (WuThi + WuTlo) + bu ----
// recipe (flash-proven): mfma(af, bf) with af = A[t0+q15][32kt+8g+j], bf = B[16nt+q15][32kt+8g+j]
// -> D[r] at lane (g,q15) = out[t0 + 4g + r][16nt + q15]
__global__ __launch_bounds__(128) void outproj_kernel(
    const unsigned short* __restrict__ Oint, const unsigned short* __restrict__ WuThi,
    const unsigned short* __restrict__ WuTlo, const float* __restrict__ bu,
    float* __restrict__ out)
{
  const int t = threadIdx.x;
  const int w = t >> 6, l = t & 63, g = l >> 4, q15 = l & 15;
  const int t0 = (blockIdx.x * 2 + w) * 16;    // 256 blocks x 2 waves -> rows 0..8191
  const f32x4 z4 = (f32x4){0.f,0.f,0.f,0.f};
  f32x4 acc[4] = {z4, z4, z4, z4};

  #pragma unroll 2
  for (int kt = 0; kt < 16; ++kt) {
    const short8 af = *(const short8*)&Oint[(size_t)(t0 + q15)*512 + kt*32 + g*8];
    #pragma unroll
    for (int nt = 0; nt < 4; ++nt) {
      const short8 bh_ = *(const short8*)&WuThi[(size_t)(nt*16 + q15)*512 + kt*32 + g*8];
      const short8 bl_ = *(const short8*)&WuTlo[(size_t)(nt*16 + q15)*512 + kt*32 + g*8];
      acc[nt] = __builtin_amdgcn_mfma_f32_16x16x32_bf16(af, bh_, acc[nt], 0,0,0);
      acc[nt] = __builtin_amdgcn_mfma_f32_16x16x32_bf16(af, bl_, acc[nt], 0,0,0);
    }
  }

  #pragma unroll
  for (int nt = 0; nt < 4; ++nt) {
    const float bv = bu[nt*16 + q15];
    #pragma unroll
    for (int r = 0; r < 4; ++r)
      out[(size_t)(t0 + 4*g + r)*EMB + nt*16 + q15] = acc[nt][r] + bv;
  }
}

extern "C" void kernel_launch(void* const* d_in, const int* in_sizes, int n_in,
                              void* d_out, int out_size, void* d_ws, size_t ws_size,
                              hipStream_t stream) {
  const float* x   = (const float*)d_in[0];
  const float* y   = (const float*)d_in[1];
  const int*   mask= (const int*)d_in[2];
  const float* Wk  = (const float*)d_in[3];
  const float* Wq  = (const float*)d_in[4];
  const float* Wv  = (const float*)d_in[5];
  const float* Wu  = (const float*)d_in[6];
  const float* bu  = (const float*)d_in[7];
  float* out = (float*)d_out;

  // ws: Qbuf(8M) | Kbuf(8M) | VbufT(8M) | Pmask(8M) | Oint bf16(8M) | WuThi(64K) | WuTlo(64K)
  unsigned short* Qbuf  = (unsigned short*)d_ws;
  unsigned short* Kbuf  = Qbuf + (size_t)32*SEQ*EMB;
  unsigned short* VbufT = Kbuf + (size_t)32*SEQ*EMB;
  u32* Pmask = (u32*)((char*)d_ws + (size_t)24*1024*1024);
  unsigned short* Oint  = (unsigned short*)((char*)d_ws + (size_t)32*1024*1024);
  unsigned short* WuThi = (unsigned short*)((char*)d_ws + (size_t)40*1024*1024);
  unsigned short* WuTlo = WuThi + 32768;

  prep_kernel<<<dim3(128, 8, 4), 256, 0, stream>>>(x, y, Wk, Wq, Wv, mask, Wu,
                                                   Kbuf, Qbuf, VbufT, Pmask, WuThi, WuTlo);
  flash_kernel<<<1024, 256, 0, stream>>>(Qbuf, Kbuf, VbufT, Pmask, Oint);
  outproj_kernel<<<256, 128, 0, stream>>>(Oint, WuThi, WuTlo, bu, out);
}

// Round 11
// 98.910 us; speedup vs baseline: 1.3411x; 1.0266x over previous
//
#include <hip/hip_runtime.h>

#define EMB 64
#define HEADS 8
#define SEQ 2048
#define LSF 68

typedef short short8 __attribute__((ext_vector_type(8)));
typedef float f32x4 __attribute__((ext_vector_type(4)));
typedef unsigned int u32;

__device__ __forceinline__ float4 ld4(const float* p) { return *(const float4*)p; }
__device__ __forceinline__ float4 fmad4(float4 a, float s, float4 c) {
  c.x += a.x*s; c.y += a.y*s; c.z += a.z*s; c.w += a.w*s; return c;
}
__device__ __forceinline__ unsigned short f2bf(float f) {
  union { float f; unsigned u; } x; x.f = f;
  return (unsigned short)((x.u + 0x7fffu + ((x.u >> 16) & 1u)) >> 16);
}
__device__ __forceinline__ float bf2f(unsigned short s) {
  union { unsigned u; float f; } x; x.u = ((unsigned)s) << 16;
  return x.f;
}
__device__ __forceinline__ float bits2f(u32 u) {
  union { u32 u; float f; } x; x.u = u;
  return x.f;
}
__device__ __forceinline__ u32 cvtpk(float lo, float hi) {
  u32 r;
  asm("v_cvt_pk_bf16_f32 %0, %1, %2" : "=v"(r) : "v"(lo), "v"(hi));
  return r;
}
__device__ __forceinline__ float vexp2(float x) {
  float r;
  asm("v_exp_f32 %0, %1" : "=v"(r) : "v"(x));
  return r;
}
__device__ __forceinline__ void gload16(const void* g, void* l) {
  __builtin_amdgcn_global_load_lds((const __attribute__((address_space(1))) unsigned int*)g,
                                   (__attribute__((address_space(3))) unsigned int*)l, 16, 0, 0);
}

#define LOG2E 1.4426950408889634f
#define NC0  (-5.770780163555854f)   /* -4 * log2(e) */

// ---- fused prep: z=0 K proj, z=1 V^T proj, z=2 Q proj, z=3 mask pack (R8 layout) + WuT ----
__global__ __launch_bounds__(256) void prep_kernel(
    const float* __restrict__ x, const float* __restrict__ y,
    const float* __restrict__ Wk, const float* __restrict__ Wq, const float* __restrict__ Wv,
    const int* __restrict__ mask, const float* __restrict__ Wu,
    unsigned short* __restrict__ Kbuf, unsigned short* __restrict__ Qbuf,
    unsigned short* __restrict__ VbufT, u32* __restrict__ pmask,
    unsigned short* __restrict__ WuThi, unsigned short* __restrict__ WuTlo)
{
  __shared__ float As[64][LSF];
  __shared__ float Bs[64][LSF];
  const int t = threadIdx.x;
  const int z = blockIdx.z;        // 0:K 1:V^T 2:Q 3:maskpack(+WuT)

  if (z == 3) {
    const int bid = blockIdx.x * 8 + blockIdx.y;     // 0..1023
    #pragma unroll
    for (int it = 0; it < 8; ++it) {
      // R8-proven packmask indexing (matched pair with R8 flash):
      // q = qblk*64 + w*16 + (l&15); k = kt*64 + 16c + 4g + 2rr
      const int gid = bid * 2048 + it * 256 + t;     // 2M words
      const int i = gid & 7, ll = (gid >> 3) & 63, ww = (gid >> 9) & 3;
      const int kt = (gid >> 11) & 31, qblk = gid >> 16;
      const int qq = qblk*64 + ww*16 + (ll & 15);
      const int g = ll >> 4, c = i >> 1, rr = i & 1;
      const int kk = kt*64 + 16*c + 4*g + 2*rr;
      const int2 mm = *(const int2*)&mask[(size_t)qq * SEQ + kk];
      pmask[gid] = (mm.x ? 0xFFFFu : 0u) | (mm.y ? 0xFFFF0000u : 0u);
    }
    if (blockIdx.y == 7) {
      // WuT split-precision: WuT[n][k] = Wu[k][n] as hi + lo bf16 planes
      const int idx = blockIdx.x * 256 + t;          // 0..32767
      const int k = idx >> 6, n = idx & 63;
      const float wv = Wu[(size_t)k * EMB + n];
      const unsigned short hi = f2bf(wv);
      const unsigned short lo = f2bf(wv - bf2f(hi));
      WuThi[(size_t)n * 512 + k] = hi;
      WuTlo[(size_t)n * 512 + k] = lo;
    }
    return;
  }

  const int rowblk = blockIdx.x;   // 0..127 over B*T/64
  const int h = blockIdx.y;        // 0..7
  const float* __restrict__ in = (z == 2) ? y : x;
  const float* __restrict__ W = (z == 0) ? Wk : (z == 1) ? Wv : Wq;

  for (int i = t; i < 1024; i += 256) {
    const int r = i >> 4, c4 = (i & 15) << 2;
    *(float4*)&As[r][c4] = ld4(&in[(size_t)(rowblk*64 + r)*EMB + c4]);
    *(float4*)&Bs[r][c4] = ld4(&W[(size_t)r*(EMB*HEADS) + h*EMB + c4]);
  }
  __syncthreads();

  const int tr = (t >> 4) << 2;
  const int tc = (t & 15) << 2;
  float4 acc[4];
  #pragma unroll
  for (int i = 0; i < 4; ++i) acc[i] = (float4){0,0,0,0};
  #pragma unroll 8
  for (int k = 0; k < 64; ++k) {
    const float4 w = *(const float4*)&Bs[k][tc];
    #pragma unroll
    for (int i = 0; i < 4; ++i) acc[i] = fmad4(w, As[tr+i][k], acc[i]);
  }

  const int b = rowblk >> 5;
  const int tbase = (rowblk & 31) * 64;
  const int bh = b * HEADS + h;
  const float scale = (z == 2) ? 0.125f : 1.0f;

  if (z != 1) {
    unsigned short* __restrict__ dst = (z == 0) ? Kbuf : Qbuf;
    #pragma unroll
    for (int i = 0; i < 4; ++i) {
      ushort4 o;
      o.x = f2bf(acc[i].x * scale); o.y = f2bf(acc[i].y * scale);
      o.z = f2bf(acc[i].z * scale); o.w = f2bf(acc[i].w * scale);
      *(ushort4*)&dst[((size_t)bh*SEQ + tbase + tr + i)*EMB + tc] = o;
    }
  } else {
    __syncthreads();
    #pragma unroll
    for (int i = 0; i < 4; ++i) {
      As[tc+0][tr+i] = acc[i].x; As[tc+1][tr+i] = acc[i].y;
      As[tc+2][tr+i] = acc[i].z; As[tc+3][tr+i] = acc[i].w;
    }
    __syncthreads();
    #pragma unroll
    for (int i = 0; i < 4; ++i) {   // row tr+i = feature
      ushort4 o;
      o.x = f2bf(As[tr+i][tc+0]); o.y = f2bf(As[tr+i][tc+1]);
      o.z = f2bf(As[tr+i][tc+2]); o.w = f2bf(As[tr+i][tc+3]);
      *(ushort4*)&VbufT[((size_t)bh*EMB + tr + i)*SEQ + tbase + tc] = o;
    }
  }
}

// ---- flash: R10 fragments/layout; single barrier per tile (mid-barrier removed: P is
// wave-private, same-wave DS ordering is HW-guaranteed), early STAGE, mask prefetch,
// setprio around MFMA clusters ----
__global__ __launch_bounds__(256, 4) void flash_kernel(
    const unsigned short* __restrict__ Qbuf, const unsigned short* __restrict__ Kbuf,
    const unsigned short* __restrict__ VbufT, const u32* __restrict__ Pmask,
    unsigned short* __restrict__ Oint)
{
  __shared__ alignas(16) char smem[40960];
  char* const K0 = smem;
  char* const K1 = smem + 8192;
  char* const V0 = smem + 16384;
  char* const V1 = smem + 24576;

  const int t = threadIdx.x;
  const int w = t >> 6, l = t & 63, g = l >> 4, q = l & 15;
  const int id = blockIdx.x;
  const int k_ = id >> 3;
  const int bh = (id & 7) * 4 + (k_ >> 5);   // XCD-aware: per-XCD K/V L2-resident
  const int qblk = k_ & 31;
  const int b = bh >> 3, h = bh & 7;

  short8 qf[2];
  {
    const unsigned short* qp = Qbuf + ((size_t)bh*SEQ + qblk*64 + w*16 + q)*EMB + g*8;
    qf[0] = *(const short8*)qp;
    qf[1] = *(const short8*)(qp + 32);
  }

  f32x4 oacc[4];
  #pragma unroll
  for (int c = 0; c < 4; ++c) oacc[c] = (f32x4){0.f,0.f,0.f,0.f};
  const f32x4 z4 = (f32x4){0.f,0.f,0.f,0.f};
  float lsum = 0.f;

  char* const Pw = smem + 32768 + w*2048;    // wave-private P: 16 rows x 128B
  const int sw = (q & 7) << 4;

  const u32* mp = Pmask + ((size_t)(qblk*128 + w))*512 + l*8;

  const int unit0 = w*64 + l, unit1 = 256 + w*64 + l;
  const int row0 = unit0 >> 3, row1 = unit1 >> 3;
  const int gs0 = (unit0 & 7) ^ (row0 & 7), gs1 = (unit1 & 7) ^ (row1 & 7);
  const unsigned short* kp0 = Kbuf + ((size_t)bh*SEQ + row0)*EMB + gs0*8;
  const unsigned short* kp1 = Kbuf + ((size_t)bh*SEQ + row1)*EMB + gs1*8;
  const unsigned short* vp0 = VbufT + ((size_t)bh*EMB + row0)*SEQ + gs0*8;
  const unsigned short* vp1 = VbufT + ((size_t)bh*EMB + row1)*SEQ + gs1*8;

  #define STAGE(KDST, VDST) do {                                                      \
    gload16(kp0, (KDST) + (w*64)*16);                                                 \
    gload16(vp0, (VDST) + (w*64)*16);                                                 \
    gload16(kp1, (KDST) + (256 + w*64)*16);                                           \
    gload16(vp1, (VDST) + (256 + w*64)*16);                                           \
    kp0 += 64*EMB; kp1 += 64*EMB; vp0 += 64; vp1 += 64;                               \
  } while (0)

  STAGE(K0, V0);
  __syncthreads();

  // current-tile mask regs (prefetched one tile ahead inside TILE)
  uint4 mw0 = *(const uint4*)mp;
  uint4 mw1 = *(const uint4*)(mp + 4);
  mp += 2048;

  #define TILE(kbase, vbase, DOSTAGE, nkdst, nvdst) do {                               \
    f32x4 sacc[4];                                                                     \
    __builtin_amdgcn_s_setprio(1);                                                     \
    _Pragma("unroll") for (int c = 0; c < 4; ++c) {                                    \
      const short8 kf0 = *(const short8*)((kbase) + (16*c + q)*128 + ((g<<4) ^ sw));   \
      const short8 kf1 = *(const short8*)((kbase) + (16*c + q)*128 + (((4+g)<<4) ^ sw));\
      sacc[c] = __builtin_amdgcn_mfma_f32_16x16x32_bf16(kf0, qf[0], z4, 0,0,0);        \
      sacc[c] = __builtin_amdgcn_mfma_f32_16x16x32_bf16(kf1, qf[1], sacc[c], 0,0,0);   \
    }                                                                                  \
    __builtin_amdgcn_s_setprio(0);                                                     \
    if (DOSTAGE) { STAGE(nkdst, nvdst); }   /* early: hides under softmax+PV */        \
    uint4 mn0 = mw0, mn1 = mw1;                                                        \
    if (DOSTAGE) { mn0 = *(const uint4*)mp; mn1 = *(const uint4*)(mp + 4); mp += 2048; } \
    u32 pw[8];                                                                         \
    _Pragma("unroll") for (int c = 0; c < 4; ++c) {                                    \
      const float p0 = vexp2(fmaf(sacc[c][0], LOG2E, NC0));                            \
      const float p1 = vexp2(fmaf(sacc[c][1], LOG2E, NC0));                            \
      const float p2 = vexp2(fmaf(sacc[c][2], LOG2E, NC0));                            \
      const float p3 = vexp2(fmaf(sacc[c][3], LOG2E, NC0));                            \
      pw[2*c]   = cvtpk(p0, p1);                                                       \
      pw[2*c+1] = cvtpk(p2, p3);                                                       \
    }                                                                                  \
    pw[0] &= mw0.x; pw[1] &= mw0.y; pw[2] &= mw0.z; pw[3] &= mw0.w;                    \
    pw[4] &= mw1.x; pw[5] &= mw1.y; pw[6] &= mw1.z; pw[7] &= mw1.w;                    \
    _Pragma("unroll") for (int c = 0; c < 4; ++c)                                      \
      *(uint2*)(Pw + ((q*128 + 32*c + 8*g) ^ sw)) = make_uint2(pw[2*c], pw[2*c+1]);    \
    float ts = 0.f;                                                                    \
    _Pragma("unroll") for (int i = 0; i < 8; ++i)                                      \
      ts += bits2f(pw[i] << 16) + bits2f(pw[i] & 0xFFFF0000u);                         \
    ts += __shfl_xor(ts, 16);                                                          \
    ts += __shfl_xor(ts, 32);                                                          \
    lsum += ts;                                                                        \
    __builtin_amdgcn_sched_barrier(0);  /* pf reads must not hoist above P writes */   \
    short8 pf[2];                                                                      \
    pf[0] = *(const short8*)(Pw + ((q*128 + 16*g) ^ sw));                              \
    pf[1] = *(const short8*)(Pw + ((q*128 + 64 + 16*g) ^ sw));                         \
    __builtin_amdgcn_s_setprio(1);                                                     \
    _Pragma("unroll") for (int c = 0; c < 4; ++c) {                                    \
      const short8 vf0 = *(const short8*)((vbase) + (16*c + q)*128 + ((g<<4) ^ sw));   \
      const short8 vf1 = *(const short8*)((vbase) + (16*c + q)*128 + (((4+g)<<4) ^ sw));\
      oacc[c] = __builtin_amdgcn_mfma_f32_16x16x32_bf16(pf[0], vf0, oacc[c], 0,0,0);   \
      oacc[c] = __builtin_amdgcn_mfma_f32_16x16x32_bf16(pf[1], vf1, oacc[c], 0,0,0);   \
    }                                                                                  \
    __builtin_amdgcn_s_setprio(0);                                                     \
    mw0 = mn0; mw1 = mn1;                                                              \
    __syncthreads();  /* single barrier: drains staged loads; separates K/V reuse */   \
  } while (0)

  #pragma unroll 1
  for (int kt2 = 0; kt2 < 16; ++kt2) {
    TILE(K0, V0, true,       K1, V1);
    TILE(K1, V1, (kt2 < 15), K0, V0);
  }
  #undef TILE
  #undef STAGE

  #pragma unroll
  for (int r = 0; r < 4; ++r) {
    const float lr = __shfl(lsum, (l & 48) | (4*g + r));
    const float inv = (lr > 1e-30f) ? 1.f / lr : 0.f;
    #pragma unroll
    for (int c = 0; c < 4; ++c) {
      Oint[((size_t)b*SEQ + qblk*64 + w*16 + 4*g + r)*(EMB*HEADS) + h*EMB + q + 16*c] =
          f2bf(oacc[c][r] * inv);
    }
  }
}

// ---- output projection via MFMA: out = Oint(bf16) @ (WuThi + WuTlo) + bu ----
__global__ __launch_bounds__(128) void outproj_kernel(
    const unsigned short* __restrict__ Oint, const unsigned short* __restrict__ WuThi,
    const unsigned short* __restrict__ WuTlo, const float* __restrict__ bu,
    float* __restrict__ out)
{
  const int t = threadIdx.x;
  const int w = t >> 6, l = t & 63, g = l >> 4, q15 = l & 15;
  const int t0 = (blockIdx.x * 2 + w) * 16;    // 256 blocks x 2 waves -> rows 0..8191
  const f32x4 z4 = (f32x4){0.f,0.f,0.f,0.f};
  f32x4 acc[4] = {z4, z4, z4, z4};

  #pragma unroll 2
  for (int kt = 0; kt < 16; ++kt) {
    const short8 af = *(const short8*)&Oint[(size_t)(t0 + q15)*512 + kt*32 + g*8];
    #pragma unroll
    for (int nt = 0; nt < 4; ++nt) {
      const short8 bh_ = *(const short8*)&WuThi[(size_t)(nt*16 + q15)*512 + kt*32 + g*8];
      const short8 bl_ = *(const short8*)&WuTlo[(size_t)(nt*16 + q15)*512 + kt*32 + g*8];
      acc[nt] = __builtin_amdgcn_mfma_f32_16x16x32_bf16(af, bh_, acc[nt], 0,0,0);
      acc[nt] = __builtin_amdgcn_mfma_f32_16x16x32_bf16(af, bl_, acc[nt], 0,0,0);
    }
  }

  #pragma unroll
  for (int nt = 0; nt < 4; ++nt) {
    const float bv = bu[nt*16 + q15];
    #pragma unroll
    for (int r = 0; r < 4; ++r)
      out[(size_t)(t0 + 4*g + r)*EMB + nt*16 + q15] = acc[nt][r] + bv;
  }
}

extern "C" void kernel_launch(void* const* d_in, const int* in_sizes, int n_in,
                              void* d_out, int out_size, void* d_ws, size_t ws_size,
                              hipStream_t stream) {
  const float* x   = (const float*)d_in[0];
  const float* y   = (const float*)d_in[1];
  const int*   mask= (const int*)d_in[2];
  const float* Wk  = (const float*)d_in[3];
  const float* Wq  = (const float*)d_in[4];
  const float* Wv  = (const float*)d_in[5];
  const float* Wu  = (const float*)d_in[6];
  const float* bu  = (const float*)d_in[7];
  float* out = (float*)d_out;

  // ws: Qbuf(8M) | Kbuf(8M) | VbufT(8M) | Pmask(8M) | Oint bf16(8M) | WuThi(64K) | WuTlo(64K)
  unsigned short* Qbuf  = (unsigned short*)d_ws;
  unsigned short* Kbuf  = Qbuf + (size_t)32*SEQ*EMB;
  unsigned short* VbufT = Kbuf + (size_t)32*SEQ*EMB;
  u32* Pmask = (u32*)((char*)d_ws + (size_t)24*1024*1024);
  unsigned short* Oint  = (unsigned short*)((char*)d_ws + (size_t)32*1024*1024);
  unsigned short* WuThi = (unsigned short*)((char*)d_ws + (size_t)40*1024*1024);
  unsigned short* WuTlo = WuThi + 32768;

  prep_kernel<<<dim3(128, 8, 4), 256, 0, stream>>>(x, y, Wk, Wq, Wv, mask, Wu,
                                                   Kbuf, Qbuf, VbufT, Pmask, WuThi, WuTlo);
  flash_kernel<<<1024, 256, 0, stream>>>(Qbuf, Kbuf, VbufT, Pmask, Oint);
  outproj_kernel<<<256, 128, 0, stream>>>(Oint, WuThi, WuTlo, bu, out);
}